// Round 1
// baseline (51.172 us; speedup 1.0000x reference)
//
#include <hip/hip_runtime.h>

#define WSZ 64

__global__ __launch_bounds__(256) void sq_reupload_kernel(
    const float* __restrict__ x,
    const float* __restrict__ theta,
    const float* __restrict__ w,
    const float* __restrict__ bias,
    float* __restrict__ out,
    int nrows)
{
    // Per-step combined RZ*RY coefficients, shared across all rows.
    // RZ(th1)*RY(th0) applied after RX: only 4 real products needed per step.
    __shared__ float4 tc[WSZ];
    int tid = threadIdx.x;
    if (tid < WSZ) {
        float th0 = 0.5f * theta[2 * tid + 0];
        float th1 = 0.5f * theta[2 * tid + 1];
        float cy = cosf(th0), sy = sinf(th0);
        float cz = cosf(th1), sz = sinf(th1);
        tc[tid] = make_float4(cy * cz, cy * sz, sy * cz, sy * sz);
    }
    __syncthreads();

    int row = blockIdx.x * blockDim.x + tid;
    if (row >= nrows) return;

    // Load the whole 64-float row as 16 x float4 (wave covers contiguous 16KB).
    const float4* xrow = reinterpret_cast<const float4*>(x) + (size_t)row * (WSZ / 4);
    float xv[WSZ];
    #pragma unroll
    for (int k = 0; k < WSZ / 4; ++k) {
        float4 v = xrow[k];
        xv[4 * k + 0] = v.x;
        xv[4 * k + 1] = v.y;
        xv[4 * k + 2] = v.z;
        xv[4 * k + 3] = v.w;
    }

    // State |psi> = (s0, s1), complex, starts at |0>.
    float s0r = 1.0f, s0i = 0.0f, s1r = 0.0f, s1i = 0.0f;

    #pragma unroll
    for (int t = 0; t < WSZ; ++t) {
        float s, c;
        __sincosf(0.5f * xv[t], &s, &c);
        // RX(xt): n0 = c*s0 - i*s*s1 ; n1 = -i*s*s0 + c*s1
        float n0r = c * s0r + s * s1i;
        float n0i = c * s0i - s * s1r;
        float n1r = s * s0i + c * s1r;
        float n1i = c * s1i - s * s0r;
        // Combined RZ*RY:
        // s0' = (cycz - i*cysz)*n0 - (sycz - i*sysz)*n1
        // s1' = (sycz + i*sysz)*n0 + (cycz + i*cysz)*n1
        float4 tt = tc[t];  // uniform address -> LDS broadcast
        float cycz = tt.x, cysz = tt.y, sycz = tt.z, sysz = tt.w;
        s0r = cycz * n0r + cysz * n0i - sycz * n1r - sysz * n1i;
        s0i = cycz * n0i - cysz * n0r - sycz * n1i + sysz * n1r;
        s1r = sycz * n0r - sysz * n0i + cycz * n1r - cysz * n1i;
        s1i = sycz * n0i + sysz * n0r + cycz * n1i + cysz * n1r;
    }

    // <Z> = |s0|^2 - |s1|^2 ; linear readout
    float z = (s0r * s0r + s0i * s0i) - (s1r * s1r + s1i * s1i);
    out[row] = z * w[0] + bias[0];
}

extern "C" void kernel_launch(void* const* d_in, const int* in_sizes, int n_in,
                              void* d_out, int out_size, void* d_ws, size_t ws_size,
                              hipStream_t stream) {
    const float* x     = (const float*)d_in[0];
    const float* theta = (const float*)d_in[1];
    const float* w     = (const float*)d_in[2];
    const float* b     = (const float*)d_in[3];
    float* out = (float*)d_out;

    int nrows = out_size;  // B = 524288
    int block = 256;
    int grid  = (nrows + block - 1) / block;
    sq_reupload_kernel<<<grid, block, 0, stream>>>(x, theta, w, b, out, nrows);
}

// Round 2
// 35.092 us; speedup vs baseline: 1.4582x; 1.4582x over previous
//
#include <hip/hip_runtime.h>

#define WSZ   64
#define CHUNK 32
#define BLOCK 256
#define PAD   (CHUNK + 1)   // 33: row stride in LDS floats -> conflict-free row reads

__device__ __forceinline__ void hw_sincos(float ang, float& s, float& c) {
    const float INV2PI = 0.15915494309189535f;  // v_sin/v_cos take revolutions
    float r = ang * INV2PI;
    s = __builtin_amdgcn_sinf(r);
    c = __builtin_amdgcn_cosf(r);
}

__global__ __launch_bounds__(BLOCK) void sq_reupload_kernel(
    const float* __restrict__ x,
    const float* __restrict__ theta,
    const float* __restrict__ w,
    const float* __restrict__ bias,
    float* __restrict__ out)
{
    // Per-step combined M = Rz(th1)*Ry(th0) (3x3, 8 nonzeros), shared by all rows:
    // row0: [cb*ca, -sb, cb*sa]   row1: [sb*ca, cb, sb*sa]   row2: [-sa, 0, ca]
    __shared__ float4 tA[WSZ];            // (m00, m01, m02, m10)
    __shared__ float4 tB[WSZ];            // (m11, m12, m20, m22)
    __shared__ float  xs[BLOCK * PAD];    // staged x chunk, padded rows

    const int tid = threadIdx.x;
    const int tlo = tid & 7;              // float4 slot within a row's 32-col chunk
    const int thi = tid >> 3;             // base row

    const size_t row0 = (size_t)blockIdx.x * BLOCK;
    const float* xblk = x + row0 * WSZ;

    // ---- issue chunk-0 loads (coalesced: wave covers 8 contiguous 128B rows) ----
    float4 r0[8], r1[8];
    #pragma unroll
    for (int j = 0; j < 8; ++j) {
        int rr = thi + j * 32;
        r0[j] = *reinterpret_cast<const float4*>(xblk + (size_t)rr * WSZ + tlo * 4);
    }

    // ---- theta coefficients (64 values, precise sincos, once per block) ----
    if (tid < WSZ) {
        float a = theta[2 * tid + 0];
        float b = theta[2 * tid + 1];
        float sa = sinf(a), ca = cosf(a);
        float sb = sinf(b), cb = cosf(b);
        tA[tid] = make_float4(cb * ca, -sb, cb * sa, sb * ca);
        tB[tid] = make_float4(cb, sb * sa, -sa, ca);
    }

    // ---- store chunk 0 to LDS (padded; scalar writes, ~2-way max aliasing) ----
    #pragma unroll
    for (int j = 0; j < 8; ++j) {
        int rr = thi + j * 32;
        float* p = &xs[rr * PAD + tlo * 4];
        p[0] = r0[j].x; p[1] = r0[j].y; p[2] = r0[j].z; p[3] = r0[j].w;
    }

    // ---- issue chunk-1 loads now; they fly during chunk-0 compute ----
    #pragma unroll
    for (int j = 0; j < 8; ++j) {
        int rr = thi + j * 32;
        r1[j] = *reinterpret_cast<const float4*>(xblk + (size_t)rr * WSZ + CHUNK + tlo * 4);
    }

    __syncthreads();

    // ---- Bloch-vector evolution: v = (x,y,z), |0> -> (0,0,1) ----
    float vx = 0.0f, vy = 0.0f, vz = 1.0f;
    const int rbase = tid * PAD;

    #pragma unroll
    for (int t = 0; t < CHUNK; ++t) {
        float xt = xs[rbase + t];
        float s, c;
        hw_sincos(xt, s, c);
        float y1 = c * vy - s * vz;       // Rx(xt)
        float z1 = s * vy + c * vz;
        float4 A = tA[t];                 // uniform -> LDS broadcast
        float4 Bv = tB[t];
        float nx = A.x * vx + A.y * y1 + A.z * z1;
        float ny = A.w * vx + Bv.x * y1 + Bv.y * z1;
        float nz = Bv.z * vx + Bv.w * z1; // m21 == 0
        vx = nx; vy = ny; vz = nz;
    }

    __syncthreads();

    // ---- store chunk 1, compute steps 32..63 ----
    #pragma unroll
    for (int j = 0; j < 8; ++j) {
        int rr = thi + j * 32;
        float* p = &xs[rr * PAD + tlo * 4];
        p[0] = r1[j].x; p[1] = r1[j].y; p[2] = r1[j].z; p[3] = r1[j].w;
    }

    __syncthreads();

    #pragma unroll
    for (int t = 0; t < CHUNK; ++t) {
        float xt = xs[rbase + t];
        float s, c;
        hw_sincos(xt, s, c);
        float y1 = c * vy - s * vz;
        float z1 = s * vy + c * vz;
        float4 A = tA[CHUNK + t];
        float4 Bv = tB[CHUNK + t];
        float nx = A.x * vx + A.y * y1 + A.z * z1;
        float ny = A.w * vx + Bv.x * y1 + Bv.y * z1;
        float nz = Bv.z * vx + Bv.w * z1;
        vx = nx; vy = ny; vz = nz;
    }

    out[row0 + tid] = vz * w[0] + bias[0];
}

extern "C" void kernel_launch(void* const* d_in, const int* in_sizes, int n_in,
                              void* d_out, int out_size, void* d_ws, size_t ws_size,
                              hipStream_t stream) {
    const float* x     = (const float*)d_in[0];
    const float* theta = (const float*)d_in[1];
    const float* w     = (const float*)d_in[2];
    const float* b     = (const float*)d_in[3];
    float* out = (float*)d_out;

    int nrows = out_size;                 // B = 524288 (divisible by 256)
    int grid  = (nrows + BLOCK - 1) / BLOCK;
    sq_reupload_kernel<<<grid, BLOCK, 0, stream>>>(x, theta, w, b, out);
}